// Round 11
// baseline (456.876 us; speedup 1.0000x reference)
//
#include <hip/hip_runtime.h>
#include <hip/hip_bf16.h>
#include <math.h>

#define NNODES 50000
#define NEDGE 625000
#define RREL 16
#define SCAN_NB 196   // ceil(50000/256)

typedef __attribute__((ext_vector_type(8))) short short8;
typedef __attribute__((ext_vector_type(4))) float f32x4;

__device__ __forceinline__ float bfu(ushort u) {
  return __uint_as_float(((unsigned)u) << 16);
}
__device__ __forceinline__ ushort f2b(float f) {
  __hip_bfloat16 h = __float2bfloat16(f);
  return *(ushort*)&h;
}
__device__ __forceinline__ void lds_fence() {
  asm volatile("" ::: "memory");
  __builtin_amdgcn_sched_barrier(0);
}

// ---------------- weight prep: bf16, B stored transposed (N x K, K contiguous) ----
// BTqkv: 384x128 (= in_proj_w as-is). BToutT: 128x128, BToutT[m][c] = opw[c][m]
// BT1: 1088x128. BT2: 544x64.
__global__ __launch_bounds__(256) void prep_weights(
    const float* __restrict__ ipw, const float* __restrict__ opw,
    const float* __restrict__ w1, const float* __restrict__ root1,
    const float* __restrict__ w2, const float* __restrict__ root2,
    __hip_bfloat16* __restrict__ BTqkv, __hip_bfloat16* __restrict__ BToutT,
    __hip_bfloat16* __restrict__ BT1, __hip_bfloat16* __restrict__ BT2) {
  int i = blockIdx.x * 256 + threadIdx.x;
  if (i < 49152) {
    BTqkv[i] = __float2bfloat16(ipw[i]);
  } else if (i < 65536) {
    int j = i - 49152; int m = j / 128, c = j % 128;
    BToutT[j] = __float2bfloat16(opw[c * 128 + m]);
  } else if (i < 65536 + 139264) {
    int j = i - 65536; int c = j / 128, k = j % 128;
    float v;
    if (c < 64) v = root1[k * 64 + c];
    else { int r = (c - 64) >> 6, o = (c - 64) & 63; v = w1[r * 8192 + k * 64 + o]; }
    BT1[j] = __float2bfloat16(v);
  } else if (i < 65536 + 139264 + 34816) {
    int j = i - 65536 - 139264; int c = j / 64, k = j % 64;
    float v;
    if (c < 32) v = root2[k * 32 + c];
    else { int r = (c - 32) >> 5, o = (c - 32) & 31; v = w2[r * 2048 + k * 32 + o]; }
    BT2[j] = __float2bfloat16(v);
  }
}

// ---------------- bias1' = bo @ B1 (f32), 1088 outputs --------------------------
__global__ __launch_bounds__(256) void prep_bias1(
    const float* __restrict__ opb, const float* __restrict__ w1,
    const float* __restrict__ root1, float* __restrict__ bias1) {
  int j = blockIdx.x * 256 + threadIdx.x;
  if (j >= 1088) return;
  float s = 0.f;
  if (j < 64) {
    for (int c = 0; c < 128; c++) s += opb[c] * root1[c * 64 + j];
  } else {
    int r = (j - 64) >> 6, o = (j - 64) & 63;
    for (int c = 0; c < 128; c++) s += opb[c] * w1[r * 8192 + c * 64 + o];
  }
  bias1[j] = s;
}

// ---------------- fused QKV-proj + attention -> o (no out_proj) -------------------
// One wave = 16 nodes x 2 heads (hf). Q in regs; per l: K-tile (16 MFMA) ->
// scores (shuffle reduce) -> exp -> V-tile (16 MFMA) weighted accumulate.
__global__ __launch_bounds__(256, 3) void fused_attn(
    const float* __restrict__ emb, const __hip_bfloat16* __restrict__ BTqkv,
    const float* __restrict__ ipb, __hip_bfloat16* __restrict__ o0) {
  __shared__ ushort ols[4][16 * 72];
  const ushort* BT = (const ushort*)BTqkv;
  int w = threadIdx.x >> 6, lane = threadIdx.x & 63;
  int wid = blockIdx.x * 4 + w;
  if (wid >= 6250) return;
  long nb = (long)(wid >> 1) * 16;
  const int hf = wid & 1;
  int lrow = lane & 15, lk = lane >> 4;
  ushort* cs = ols[w];

  // ---- A_0 fragments ----
  short8 af[4];
  {
    const float* ap = emb + (nb + lrow) * 128;
#pragma unroll
    for (int k0 = 0; k0 < 4; k0++) {
      float4 f0 = *(const float4*)(ap + k0 * 32 + lk * 8);
      float4 f1 = *(const float4*)(ap + k0 * 32 + lk * 8 + 4);
      int4 v;
      v.x = (int)f2b(f0.x) | ((int)f2b(f0.y) << 16);
      v.y = (int)f2b(f0.z) | ((int)f2b(f0.w) << 16);
      v.z = (int)f2b(f1.x) | ((int)f2b(f1.y) << 16);
      v.w = (int)f2b(f1.z) | ((int)f2b(f1.w) << 16);
      af[k0] = *(short8*)&v;
    }
  }

  // ---- Q = A0 x Wq^T (+bias, *1/sqrt(32)), this hf's 64 cols ----
  f32x4 Q[4];
#pragma unroll
  for (int j = 0; j < 4; j++) Q[j] = (f32x4){0.f, 0.f, 0.f, 0.f};
#pragma unroll
  for (int k0 = 0; k0 < 4; k0++) {
    short8 bfr[4];
#pragma unroll
    for (int j = 0; j < 4; j++)
      bfr[j] = *(const short8*)(BT + (long)(hf * 64 + j * 16 + lrow) * 128 + k0 * 32 + lk * 8);
#pragma unroll
    for (int j = 0; j < 4; j++)
      Q[j] = __builtin_amdgcn_mfma_f32_16x16x32_bf16(af[k0], bfr[j], Q[j], 0, 0, 0);
  }
  const float alpha = 0.17677669529663687f;
  float bk[4], bv[4];
#pragma unroll
  for (int j = 0; j < 4; j++) {
    int col = hf * 64 + j * 16 + lrow;
    float bq = ipb[col];
    bk[j] = ipb[128 + col];
    bv[j] = ipb[256 + col];
#pragma unroll
    for (int q = 0; q < 4; q++) Q[j][q] = (Q[j][q] + bq) * alpha;
  }

  f32x4 o_acc[4];
  float dsum[4][2];
#pragma unroll
  for (int j = 0; j < 4; j++) o_acc[j] = (f32x4){0.f, 0.f, 0.f, 0.f};
#pragma unroll
  for (int q = 0; q < 4; q++) { dsum[q][0] = 0.f; dsum[q][1] = 0.f; }

  for (int l = 0; l < 4; l++) {
    short8 al[4];
    {
      const float* ap = emb + ((long)l * NNODES + nb + lrow) * 128;
#pragma unroll
      for (int k0 = 0; k0 < 4; k0++) {
        float4 f0 = *(const float4*)(ap + k0 * 32 + lk * 8);
        float4 f1 = *(const float4*)(ap + k0 * 32 + lk * 8 + 4);
        int4 v;
        v.x = (int)f2b(f0.x) | ((int)f2b(f0.y) << 16);
        v.y = (int)f2b(f0.z) | ((int)f2b(f0.w) << 16);
        v.z = (int)f2b(f1.x) | ((int)f2b(f1.y) << 16);
        v.w = (int)f2b(f1.z) | ((int)f2b(f1.w) << 16);
        al[k0] = *(short8*)&v;
      }
    }
    // K-tile
    f32x4 kacc[4];
#pragma unroll
    for (int j = 0; j < 4; j++) kacc[j] = (f32x4){0.f, 0.f, 0.f, 0.f};
#pragma unroll
    for (int k0 = 0; k0 < 4; k0++) {
      short8 bfr[4];
#pragma unroll
      for (int j = 0; j < 4; j++)
        bfr[j] = *(const short8*)(BT + (long)(128 + hf * 64 + j * 16 + lrow) * 128 + k0 * 32 + lk * 8);
#pragma unroll
      for (int j = 0; j < 4; j++)
        kacc[j] = __builtin_amdgcn_mfma_f32_16x16x32_bf16(al[k0], bfr[j], kacc[j], 0, 0, 0);
    }
    // scores -> exp weights (2 heads)
    float wgt[4][2];
#pragma unroll
    for (int hh = 0; hh < 2; hh++) {
      f32x4 p;
#pragma unroll
      for (int q = 0; q < 4; q++)
        p[q] = Q[2 * hh][q] * (kacc[2 * hh][q] + bk[2 * hh]) +
               Q[2 * hh + 1][q] * (kacc[2 * hh + 1][q] + bk[2 * hh + 1]);
#pragma unroll
      for (int off = 1; off <= 8; off <<= 1) {
#pragma unroll
        for (int q = 0; q < 4; q++) p[q] += __shfl_xor(p[q], off);
      }
#pragma unroll
      for (int q = 0; q < 4; q++) {
        wgt[q][hh] = __expf(p[q]);
        dsum[q][hh] += wgt[q][hh];
      }
    }
    // V-tile, weighted accumulate
    f32x4 vacc[4];
#pragma unroll
    for (int j = 0; j < 4; j++) vacc[j] = (f32x4){0.f, 0.f, 0.f, 0.f};
#pragma unroll
    for (int k0 = 0; k0 < 4; k0++) {
      short8 bfr[4];
#pragma unroll
      for (int j = 0; j < 4; j++)
        bfr[j] = *(const short8*)(BT + (long)(256 + hf * 64 + j * 16 + lrow) * 128 + k0 * 32 + lk * 8);
#pragma unroll
      for (int j = 0; j < 4; j++)
        vacc[j] = __builtin_amdgcn_mfma_f32_16x16x32_bf16(al[k0], bfr[j], vacc[j], 0, 0, 0);
    }
#pragma unroll
    for (int j = 0; j < 4; j++) {
#pragma unroll
      for (int q = 0; q < 4; q++)
        o_acc[j][q] += wgt[q][j >> 1] * (vacc[j][q] + bv[j]);
    }
  }

  // ---- normalize, stage 16x64 (bf16) in per-wave LDS, coalesced store ----
#pragma unroll
  for (int j = 0; j < 4; j++) {
    int c = j * 16 + lrow;
#pragma unroll
    for (int q = 0; q < 4; q++)
      cs[(4 * lk + q) * 72 + c] = f2b(o_acc[j][q] / dsum[q][j >> 1]);
  }
  lds_fence();
#pragma unroll
  for (int p = 0; p < 2; p++) {
    int r = p * 8 + (lane >> 3), k = lane & 7;
    *(int4*)((ushort*)o0 + (nb + r) * 128 + hf * 64 + k * 8) = *(const int4*)(cs + r * 72 + k * 8);
  }
}

// ================== wave-autonomous GEMM (validated in r8/r10) ==================
template <int KK>
__device__ __forceinline__ void load_af_b16(
    const ushort* __restrict__ A, long row0, long M, int lrow, int lk,
    short8 af[2][KK / 32]) {
#pragma unroll
  for (int i = 0; i < 2; i++) {
    long r = row0 + 16 * i + lrow;
    if (r > M - 1) r = M - 1;
#pragma unroll
    for (int k0 = 0; k0 < KK / 32; k0++)
      af[i][k0] = *(const short8*)(A + r * KK + k0 * 32 + lk * 8);
  }
}

template <int KK>
__device__ __forceinline__ void mfma_half(
    const ushort* __restrict__ BT, int N, int col0, int lrow, int lk,
    const short8 af[2][KK / 32], f32x4 acc[2][4]) {
#pragma unroll
  for (int i = 0; i < 2; i++)
#pragma unroll
    for (int j = 0; j < 4; j++) acc[i][j] = (f32x4){0.f, 0.f, 0.f, 0.f};
#pragma unroll
  for (int k0 = 0; k0 < KK / 32; k0++) {
    short8 bfr[4];
#pragma unroll
    for (int j = 0; j < 4; j++) {
      int gn = col0 + 16 * j + lrow;
      if (gn > N - 1) gn = N - 1;
      bfr[j] = *(const short8*)(BT + (long)gn * KK + k0 * 32 + lk * 8);
    }
#pragma unroll
    for (int i = 0; i < 2; i++)
#pragma unroll
      for (int j = 0; j < 4; j++)
        acc[i][j] = __builtin_amdgcn_mfma_f32_16x16x32_bf16(af[i][k0], bfr[j], acc[i][j], 0, 0, 0);
  }
}

__device__ __forceinline__ void store_half(
    ushort* __restrict__ cs, ushort* __restrict__ C, long row0, long Meff,
    int N, int ldc, int col0, int lane, int lrow, int lk,
    const f32x4 acc[2][4], const float* __restrict__ bias) {
#pragma unroll
  for (int j = 0; j < 4; j++) {
    int c = 16 * j + lrow;
    float bv = bias ? bias[col0 + c] : 0.f;
#pragma unroll
    for (int i = 0; i < 2; i++)
#pragma unroll
      for (int q = 0; q < 4; q++)
        cs[(16 * i + 4 * lk + q) * 72 + c] = f2b(acc[i][j][q] + bv);
  }
  lds_fence();
#pragma unroll
  for (int p = 0; p < 4; p++) {
    int r = p * 8 + (lane >> 3);
    int k = lane & 7;
    long gm = row0 + r;
    int col = col0 + k * 8;
    if (gm < Meff && col < N)
      *(int4*)(C + gm * (long)ldc + col) = *(const int4*)(cs + r * 72 + k * 8);
  }
  lds_fence();
}

template <int KK>
__global__ __launch_bounds__(256, 4) void gemm_reg(
    const __hip_bfloat16* __restrict__ Av, const __hip_bfloat16* __restrict__ BTv,
    const float* __restrict__ bias, __hip_bfloat16* __restrict__ Cv,
    int M, int N, int ldc, int G) {
  __shared__ ushort Cs[4][32 * 72];
  const ushort* A = (const ushort*)Av;
  const ushort* BT = (const ushort*)BTv;
  ushort* C = (ushort*)Cv;
  int w = threadIdx.x >> 6, lane = threadIdx.x & 63;
  long wid = (long)blockIdx.x * 4 + w;
  long nrw = (M + 31) / 32;
  if (wid >= nrw) return;
  long row0 = wid * 32;
  int lrow = lane & 15, lk = lane >> 4;
  ushort* cs = Cs[w];
  short8 af[2][KK / 32];
  load_af_b16<KK>(A, row0, M, lrow, lk, af);
  f32x4 acc[2][4];
  int nh = (N + 63) / 64;
  for (int h = blockIdx.y; h < nh; h += G) {
    int col0 = h * 64;
    mfma_half<KK>(BT, N, col0, lrow, lk, af, acc);
    store_half(cs, C, row0, M, N, ldc, col0, lane, lrow, lk, acc, bias);
  }
}

// ---------------- edge counts per (r, dst) ---------------------------------------
__global__ __launch_bounds__(256) void count_edges(
    const int* __restrict__ dst, const int* __restrict__ et, int* __restrict__ cnt) {
  int e = blockIdx.x * 256 + threadIdx.x;
  if (e < NEDGE) atomicAdd(&cnt[et[e] * NNODES + dst[e]], 1);
}

// ---------------- CSR build ------------------------------------------------------
__global__ __launch_bounds__(256) void scan1(
    const int* __restrict__ cnt, int* __restrict__ off, int* __restrict__ part) {
  int t = threadIdx.x, b = blockIdx.x;
  int i = b * 256 + t;
  int v = 0;
  if (i < NNODES) {
#pragma unroll
    for (int r = 0; r < RREL; r++) v += cnt[r * NNODES + i];
  }
  __shared__ int sm[256];
  sm[t] = v;
  __syncthreads();
#pragma unroll
  for (int o = 1; o < 256; o <<= 1) {
    int x = (t >= o) ? sm[t - o] : 0;
    __syncthreads();
    sm[t] += x;
    __syncthreads();
  }
  if (i < NNODES) off[i] = sm[t] - v;
  if (t == 255) part[b] = sm[t];
}

__global__ __launch_bounds__(256) void scan2(int* __restrict__ part) {
  int t = threadIdx.x;
  int v = (t < SCAN_NB) ? part[t] : 0;
  __shared__ int sm[256];
  sm[t] = v;
  __syncthreads();
#pragma unroll
  for (int o = 1; o < 256; o <<= 1) {
    int x = (t >= o) ? sm[t - o] : 0;
    __syncthreads();
    sm[t] += x;
    __syncthreads();
  }
  if (t < SCAN_NB) part[t] = sm[t] - v;
}

__global__ __launch_bounds__(256) void scan3(int* __restrict__ off, const int* __restrict__ part) {
  int i = blockIdx.x * 256 + threadIdx.x;
  if (i < NNODES) off[i] += part[blockIdx.x];
  if (i == 0) off[NNODES] = NEDGE;
}

__global__ __launch_bounds__(256) void scatter_edges(
    const int* __restrict__ src, const int* __restrict__ dst, const int* __restrict__ et,
    const int* __restrict__ cnt, const int* __restrict__ off,
    int* __restrict__ fill, unsigned* __restrict__ sorted, float* __restrict__ scales) {
  int e = blockIdx.x * 256 + threadIdx.x;
  if (e >= NEDGE) return;
  int d = dst[e], r = et[e], s = src[e];
  int pos = off[d] + atomicAdd(&fill[d], 1);
  sorted[pos] = (unsigned)s | ((unsigned)r << 16);
  scales[pos] = 1.0f / (float)cnt[r * NNODES + d];
}

// ---------------- fused layer1: root+bias + segmented mean-agg + relu -> bf16 -----
__global__ __launch_bounds__(256) void fused1(
    const int* __restrict__ off, const unsigned* __restrict__ sorted,
    const float* __restrict__ scales, const ushort* __restrict__ Y1,
    const float* __restrict__ b1, __hip_bfloat16* __restrict__ x1b) {
  int w = threadIdx.x >> 6, lane = threadIdx.x & 63;
  int d = blockIdx.x * 4 + w;
  int s0 = off[d], s1 = off[d + 1];
  float acc = bfu(Y1[(size_t)d * 1088 + lane]) + b1[lane];
  for (int i = s0; i < s1; i++) {
    unsigned p = sorted[i];
    acc += bfu(Y1[(size_t)(p & 0xFFFF) * 1088 + 64 + (p >> 16) * 64 + lane]) * scales[i];
  }
  x1b[(size_t)d * 64 + lane] = __float2bfloat16(fmaxf(acc, 0.f));
}

// ---------------- fused layer2: root+bias + agg + softmax -> out ------------------
__global__ __launch_bounds__(256) void fused2(
    const int* __restrict__ off, const unsigned* __restrict__ sorted,
    const float* __restrict__ scales, const ushort* __restrict__ Y2,
    const float* __restrict__ b2, float* __restrict__ out) {
  int w = threadIdx.x >> 6, lane = threadIdx.x & 63;
  int d = blockIdx.x * 4 + w;
  int j = lane & 31, half = lane >> 5;
  int s0 = off[d], s1 = off[d + 1];
  float acc = 0.f;
  for (int i = s0 + half; i < s1; i += 2) {
    unsigned p = sorted[i];
    acc += bfu(Y2[(size_t)(p & 0xFFFF) * 544 + 32 + (p >> 16) * 32 + j]) * scales[i];
  }
  acc += __shfl_xor(acc, 32);
  float v = acc + bfu(Y2[(size_t)d * 544 + j]) + b2[j];
  float mx = v;
#pragma unroll
  for (int o = 16; o; o >>= 1) mx = fmaxf(mx, __shfl_xor(mx, o));
  float e = __expf(v - mx);
  float sum = e;
#pragma unroll
  for (int o = 16; o; o >>= 1) sum += __shfl_xor(sum, o);
  if (half == 0) out[(size_t)d * 32 + j] = e / sum;
}

// =================================================================================
extern "C" void kernel_launch(void* const* d_in, const int* in_sizes, int n_in,
                              void* d_out, int out_size, void* d_ws, size_t ws_size,
                              hipStream_t stream) {
  (void)in_sizes; (void)n_in; (void)out_size; (void)ws_size;
  const float* emb   = (const float*)d_in[0];
  const float* ipw   = (const float*)d_in[1];
  const float* ipb   = (const float*)d_in[2];
  const float* opw   = (const float*)d_in[3];
  const float* opb   = (const float*)d_in[4];
  const float* w1    = (const float*)d_in[5];
  const float* root1 = (const float*)d_in[6];
  const float* b1    = (const float*)d_in[7];
  const float* w2    = (const float*)d_in[8];
  const float* root2 = (const float*)d_in[9];
  const float* b2    = (const float*)d_in[10];
  const int*   eidx  = (const int*)d_in[11];
  const int*   etype = (const int*)d_in[12];
  const int* srcp = eidx;
  const int* dstp = eidx + NEDGE;

  unsigned char* ws = (unsigned char*)d_ws;
  size_t off_b = 0;
  auto alloc = [&](size_t bytes) {
    unsigned char* p = ws + off_b;
    off_b += (bytes + 255) & ~(size_t)255;
    return p;
  };

  // Region R reused sequentially: Y1 108.8MB -> Y2 54.4MB
  unsigned char* R = alloc(108800000);
  __hip_bfloat16* Y1  = (__hip_bfloat16*)R;
  __hip_bfloat16* Y2  = (__hip_bfloat16*)R;
  __hip_bfloat16* o0  = (__hip_bfloat16*)alloc(12800000);
  __hip_bfloat16* x1b = (__hip_bfloat16*)alloc(6400000);
  int*            cnt = (int*)alloc(3200000);
  int*            offs = (int*)alloc((NNODES + 1) * 4);
  int*            fill = (int*)alloc(NNODES * 4);
  int*            part = (int*)alloc(SCAN_NB * 4);
  unsigned*       sorted = (unsigned*)alloc(NEDGE * 4);
  float*          scales = (float*)alloc(NEDGE * 4);
  __hip_bfloat16* BTqkv  = (__hip_bfloat16*)alloc(98304);
  __hip_bfloat16* BToutT = (__hip_bfloat16*)alloc(32768);
  __hip_bfloat16* BT1    = (__hip_bfloat16*)alloc(278528);
  __hip_bfloat16* BT2    = (__hip_bfloat16*)alloc(69632);
  __hip_bfloat16* BW     = (__hip_bfloat16*)alloc(278528);  // 1088 x 128
  float*          bias1  = (float*)alloc(4352);

  // 1) weight prep + CSR build
  prep_weights<<<dim3((241664 + 255) / 256), dim3(256), 0, stream>>>(
      ipw, opw, w1, root1, w2, root2, BTqkv, BToutT, BT1, BT2);
  prep_bias1<<<dim3(5), dim3(256), 0, stream>>>(opb, w1, root1, bias1);
  hipMemsetAsync(cnt, 0, (size_t)RREL * NNODES * sizeof(int), stream);
  hipMemsetAsync(fill, 0, (size_t)NNODES * sizeof(int), stream);
  count_edges<<<dim3((NEDGE + 255) / 256), dim3(256), 0, stream>>>(dstp, etype, cnt);
  scan1<<<dim3(SCAN_NB), dim3(256), 0, stream>>>(cnt, offs, part);
  scan2<<<dim3(1), dim3(256), 0, stream>>>(part);
  scan3<<<dim3(SCAN_NB), dim3(256), 0, stream>>>(offs, part);
  scatter_edges<<<dim3((NEDGE + 255) / 256), dim3(256), 0, stream>>>(
      srcp, dstp, etype, cnt, offs, fill, sorted, scales);

  // 2) BW = B1^T @ Wo^T fold: (1088 x 128) @ (128 x 128), A = BT1, BT = BToutT
  gemm_reg<128><<<dim3(9, 1), dim3(256), 0, stream>>>(
      BT1, BToutT, nullptr, BW, 1088, 128, 128, 1);

  // 3) fused QKV + attention -> o0 (6250 waves: 16 nodes x 2 heads each)
  fused_attn<<<dim3(1563), dim3(256), 0, stream>>>(emb, BTqkv, ipb, o0);

  // 4) Y1 = o0 @ BW (+bias1'): (50000 x 128) @ (128 x 1088)
  gemm_reg<128><<<dim3(391, 8), dim3(256), 0, stream>>>(
      o0, BW, bias1, Y1, NNODES, 1088, 1088, 8);

  // 5) fused layer1 -> x1b
  fused1<<<dim3(NNODES / 4), dim3(256), 0, stream>>>(
      offs, sorted, scales, (const ushort*)Y1, b1, x1b);

  // 6) Y2 = x1b @ [root2 | W2_r]: (50000 x 64) @ (64 x 544)
  gemm_reg<64><<<dim3(391, 4), dim3(256), 0, stream>>>(
      x1b, BT2, nullptr, Y2, NNODES, 544, 544, 4);

  // 7) fused layer2 + softmax -> out
  fused2<<<dim3(NNODES / 4), dim3(256), 0, stream>>>(
      offs, sorted, scales, (const ushort*)Y2, b2, (float*)d_out);
}

// Round 12
// 340.242 us; speedup vs baseline: 1.3428x; 1.3428x over previous
//
#include <hip/hip_runtime.h>
#include <hip/hip_bf16.h>
#include <math.h>

#define NNODES 50000
#define NEDGE 625000
#define RREL 16
#define SCAN_NB 196   // ceil(50000/256)

typedef __attribute__((ext_vector_type(8))) short short8;
typedef __attribute__((ext_vector_type(4))) float f32x4;

__device__ __forceinline__ float bfu(ushort u) {
  return __uint_as_float(((unsigned)u) << 16);
}
__device__ __forceinline__ ushort f2b(float f) {
  __hip_bfloat16 h = __float2bfloat16(f);
  return *(ushort*)&h;
}

// ---------------- weight prep: bf16, B stored transposed (N x K, K contiguous) ----
// BTqkv: 384x128 (= in_proj_w as-is). BToutT[m][c] = opw[c*128+m] (for BW fold).
// BT1: 1088x128. BT2: 544x64.
__global__ __launch_bounds__(256) void prep_weights(
    const float* __restrict__ ipw, const float* __restrict__ opw,
    const float* __restrict__ w1, const float* __restrict__ root1,
    const float* __restrict__ w2, const float* __restrict__ root2,
    __hip_bfloat16* __restrict__ BTqkv, __hip_bfloat16* __restrict__ BToutT,
    __hip_bfloat16* __restrict__ BT1, __hip_bfloat16* __restrict__ BT2) {
  int i = blockIdx.x * 256 + threadIdx.x;
  if (i < 49152) {
    BTqkv[i] = __float2bfloat16(ipw[i]);
  } else if (i < 65536) {
    int j = i - 49152; int m = j / 128, c = j % 128;
    BToutT[j] = __float2bfloat16(opw[c * 128 + m]);
  } else if (i < 65536 + 139264) {
    int j = i - 65536; int c = j / 128, k = j % 128;
    float v;
    if (c < 64) v = root1[k * 64 + c];
    else { int r = (c - 64) >> 6, o = (c - 64) & 63; v = w1[r * 8192 + k * 64 + o]; }
    BT1[j] = __float2bfloat16(v);
  } else if (i < 65536 + 139264 + 34816) {
    int j = i - 65536 - 139264; int c = j / 64, k = j % 64;
    float v;
    if (c < 32) v = root2[k * 32 + c];
    else { int r = (c - 32) >> 5, o = (c - 32) & 31; v = w2[r * 2048 + k * 32 + o]; }
    BT2[j] = __float2bfloat16(v);
  }
}

// ---------------- bias1' = bo @ B1 (f32), 1088 outputs ----------------------------
__global__ __launch_bounds__(256) void prep_bias1(
    const float* __restrict__ opb, const float* __restrict__ w1,
    const float* __restrict__ root1, float* __restrict__ bias1) {
  int j = blockIdx.x * 256 + threadIdx.x;
  if (j >= 1088) return;
  float s = 0.f;
  if (j < 64) {
    for (int c = 0; c < 128; c++) s += opb[c] * root1[c * 64 + j];
  } else {
    int r = (j - 64) >> 6, o = (j - 64) & 63;
    for (int c = 0; c < 128; c++) s += opb[c] * w1[r * 8192 + c * 64 + o];
  }
  bias1[j] = s;
}

// ---------------- QKV GEMM: strip-loop, A staged ONCE per row panel (r6, 97us) ----
__global__ __launch_bounds__(256) void qkv_gemm(
    const float* __restrict__ A, const __hip_bfloat16* __restrict__ BT,
    const float* __restrict__ bias, __hip_bfloat16* __restrict__ C) {
  __shared__ ushort As[128 * 128];   // 32KB
  __shared__ ushort Cs[128 * 136];   // 34.8KB padded C staging
  const int t = threadIdx.x;
  const long row0 = (long)blockIdx.x * 128;

#pragma unroll
  for (int c = t; c < 128 * 16; c += 256) {
    int r = c >> 4, cc = c & 15;
    long gm = row0 + r;
    int4 v = make_int4(0, 0, 0, 0);
    if (gm < 200000) {
      const float* ap = A + gm * 128 + cc * 8;
      float4 f0 = *(const float4*)ap;
      float4 f1 = *(const float4*)(ap + 4);
      v.x = (int)f2b(f0.x) | ((int)f2b(f0.y) << 16);
      v.y = (int)f2b(f0.z) | ((int)f2b(f0.w) << 16);
      v.z = (int)f2b(f1.x) | ((int)f2b(f1.y) << 16);
      v.w = (int)f2b(f1.z) | ((int)f2b(f1.w) << 16);
    }
    *(int4*)(As + r * 128 + ((cc ^ (r & 7)) * 8)) = v;
  }
  __syncthreads();

  const int lane = t & 63, w = t >> 6;
  const int wr = (w >> 1) * 64, wc = (w & 1) * 64;
  const int lrow = lane & 15, lk = lane >> 4;
  const int nstrips = (row0 < NNODES) ? 3 : 2;

  for (int s = 0; s < nstrips; s++) {
    const int col0 = (s == 2) ? 0 : 128 + s * 128;
    const long Meff = (s == 2) ? NNODES : 200000;

    const ushort* bp[4];
#pragma unroll
    for (int j = 0; j < 4; j++)
      bp[j] = (const ushort*)BT + (long)(col0 + wc + j * 16 + lrow) * 128 + lk * 8;

    f32x4 acc[4][4];
#pragma unroll
    for (int i = 0; i < 4; i++)
#pragma unroll
      for (int j = 0; j < 4; j++) acc[i][j] = (f32x4){0.f, 0.f, 0.f, 0.f};

#pragma unroll
    for (int k0 = 0; k0 < 128; k0 += 32) {
      const int cb = k0 / 8 + lk;
      short8 af[4], bfr[4];
#pragma unroll
      for (int j = 0; j < 4; j++) bfr[j] = *(const short8*)(bp[j] + k0);
#pragma unroll
      for (int i = 0; i < 4; i++) {
        int ra = wr + i * 16 + lrow;
        af[i] = *(const short8*)(As + ra * 128 + ((cb ^ (ra & 7)) * 8));
      }
#pragma unroll
      for (int i = 0; i < 4; i++)
#pragma unroll
        for (int j = 0; j < 4; j++)
          acc[i][j] = __builtin_amdgcn_mfma_f32_16x16x32_bf16(af[i], bfr[j], acc[i][j], 0, 0, 0);
    }

    __syncthreads();  // Cs free (prev strip's stores done)
#pragma unroll
    for (int j = 0; j < 4; j++) {
      int coll = wc + j * 16 + lrow;
      float bv = bias[col0 + coll];
#pragma unroll
      for (int i = 0; i < 4; i++) {
        int rbase = wr + i * 16 + lk * 4;
#pragma unroll
        for (int q = 0; q < 4; q++)
          Cs[(rbase + q) * 136 + coll] = f2b(acc[i][j][q] + bv);
      }
    }
    __syncthreads();
#pragma unroll
    for (int idx = t; idx < 128 * 16; idx += 256) {
      int r = idx >> 4, k = idx & 15;
      long gm = row0 + r;
      if (gm < Meff)
        *(int4*)((ushort*)C + gm * 384 + col0 + k * 8) = *(const int4*)(Cs + r * 136 + k * 8);
    }
  }
}

// ---------------- generic strip-loop bf16 GEMM (B direct from L2) -----------------
#define EPILOGUE_STORE(MEFF, NCOLS, LDC, BIASEXPR)                              \
  for (int p = 0; p < 2; p++) {                                                 \
    __syncthreads();                                                            \
    if ((w >> 1) == p) {                                                        \
      _Pragma("unroll")                                                         \
      for (int j = 0; j < 4; j++) {                                             \
        int coll = wc + j * 16 + lrow;                                          \
        float bv = (BIASEXPR);                                                  \
        _Pragma("unroll")                                                       \
        for (int i = 0; i < 4; i++) {                                           \
          int rloc = i * 16 + lk * 4;                                           \
          _Pragma("unroll")                                                     \
          for (int q = 0; q < 4; q++)                                           \
            Cs[(rloc + q) * 132 + coll] = f2b(acc[i][j][q] + bv);               \
        }                                                                       \
      }                                                                         \
    }                                                                           \
    __syncthreads();                                                            \
    _Pragma("unroll")                                                           \
    for (int idx = t; idx < 64 * 16; idx += 256) {                              \
      int r = idx >> 4, k = idx & 15;                                           \
      long gm = row0 + p * 64 + r;                                              \
      int col = col0 + k * 8;                                                   \
      if (gm < (MEFF) && col < (NCOLS))                                         \
        *(int4*)((ushort*)C + gm * (LDC) + col) = *(const int4*)(Cs + r * 132 + k * 8); \
    }                                                                           \
  }

template <int K>
__global__ __launch_bounds__(256) void gemm_strips(
    const __hip_bfloat16* __restrict__ Av, const __hip_bfloat16* __restrict__ BT,
    const float* __restrict__ bias, __hip_bfloat16* __restrict__ C,
    int M, int N, int ldc, int spg) {
  constexpr int CPR = K / 8;
  __shared__ ushort As[128 * K];
  __shared__ ushort Cs[64 * 132];
  const int t = threadIdx.x;
  const long row0 = (long)blockIdx.x * 128;

#pragma unroll
  for (int c = t; c < 128 * CPR; c += 256) {
    int r = c / CPR, cc = c % CPR;
    long gm = row0 + r;
    int4 v = make_int4(0, 0, 0, 0);
    if (gm < M) v = *(const int4*)((const ushort*)Av + gm * K + cc * 8);
    *(int4*)(As + r * K + ((cc ^ (r & 7)) * 8)) = v;
  }
  __syncthreads();

  const int lane = t & 63, w = t >> 6;
  const int wr = (w >> 1) * 64, wc = (w & 1) * 64;
  const int lrow = lane & 15, lk = lane >> 4;
  const int nstrips = (N + 127) / 128;
  const int sbeg = blockIdx.y * spg;
  const int send = min(sbeg + spg, nstrips);

  for (int s = sbeg; s < send; s++) {
    const int col0 = s * 128;

    const ushort* bp[4];
#pragma unroll
    for (int j = 0; j < 4; j++) {
      int gn = col0 + wc + j * 16 + lrow;
      if (gn > N - 1) gn = N - 1;
      bp[j] = (const ushort*)BT + (long)gn * K + lk * 8;
    }

    f32x4 acc[4][4];
#pragma unroll
    for (int i = 0; i < 4; i++)
#pragma unroll
      for (int j = 0; j < 4; j++) acc[i][j] = (f32x4){0.f, 0.f, 0.f, 0.f};

#pragma unroll
    for (int k0 = 0; k0 < K; k0 += 32) {
      const int cb = k0 / 8 + lk;
      short8 af[4], bfr[4];
#pragma unroll
      for (int j = 0; j < 4; j++) bfr[j] = *(const short8*)(bp[j] + k0);
#pragma unroll
      for (int i = 0; i < 4; i++) {
        int ra = wr + i * 16 + lrow;
        af[i] = *(const short8*)(As + ra * K + ((cb ^ (ra & 7)) * 8));
      }
#pragma unroll
      for (int i = 0; i < 4; i++)
#pragma unroll
        for (int j = 0; j < 4; j++)
          acc[i][j] = __builtin_amdgcn_mfma_f32_16x16x32_bf16(af[i], bfr[j], acc[i][j], 0, 0, 0);
    }

    EPILOGUE_STORE(M, N, ldc, bias ? bias[min(col0 + coll, N - 1)] : 0.f)
  }
}

// ---------------- attention (only l=0 of output needed), ushort2-vectorized -------
// qkv: row (l*NNODES+n), cols: [0,128)=q, [128,256)=k, [256,384)=v, ld=384
__global__ __launch_bounds__(256) void attn_kernel(
    const __hip_bfloat16* __restrict__ qkv, __hip_bfloat16* __restrict__ o0) {
  int w = threadIdx.x >> 6, lane = threadIdx.x & 63;
  int n = blockIdx.x * 4 + w;
  const ushort* base = (const ushort*)qkv;
  uint qv = *(const uint*)(base + (size_t)n * 384 + lane * 2);
  float q0 = bfu(qv & 0xffff), q1 = bfu(qv >> 16);
  float s[4];
#pragma unroll
  for (int m = 0; m < 4; m++) {
    uint kk = *(const uint*)(base + (size_t)(m * NNODES + n) * 384 + 128 + lane * 2);
    float p = q0 * bfu(kk & 0xffff) + q1 * bfu(kk >> 16);
#pragma unroll
    for (int off = 8; off; off >>= 1) p += __shfl_xor(p, off);
    s[m] = p * 0.17677669529663687f;  // 1/sqrt(32)
  }
  float mx = fmaxf(fmaxf(s[0], s[1]), fmaxf(s[2], s[3]));
  float e[4], sum = 0.f;
#pragma unroll
  for (int m = 0; m < 4; m++) { e[m] = __expf(s[m] - mx); sum += e[m]; }
  float inv = 1.0f / sum;
  float o0f = 0.f, o1f = 0.f;
#pragma unroll
  for (int m = 0; m < 4; m++) {
    uint vv = *(const uint*)(base + (size_t)(m * NNODES + n) * 384 + 256 + lane * 2);
    float wgt = e[m] * inv;
    o0f += wgt * bfu(vv & 0xffff);
    o1f += wgt * bfu(vv >> 16);
  }
  *(uint*)((ushort*)o0 + (size_t)n * 128 + lane * 2) = (uint)f2b(o0f) | ((uint)f2b(o1f) << 16);
}

// ---------------- edge counts per (r, dst) ---------------------------------------
__global__ __launch_bounds__(256) void count_edges(
    const int* __restrict__ dst, const int* __restrict__ et, int* __restrict__ cnt) {
  int e = blockIdx.x * 256 + threadIdx.x;
  if (e < NEDGE) atomicAdd(&cnt[et[e] * NNODES + dst[e]], 1);
}

// ---------------- CSR build ------------------------------------------------------
__global__ __launch_bounds__(256) void scan1(
    const int* __restrict__ cnt, int* __restrict__ off, int* __restrict__ part) {
  int t = threadIdx.x, b = blockIdx.x;
  int i = b * 256 + t;
  int v = 0;
  if (i < NNODES) {
#pragma unroll
    for (int r = 0; r < RREL; r++) v += cnt[r * NNODES + i];
  }
  __shared__ int sm[256];
  sm[t] = v;
  __syncthreads();
#pragma unroll
  for (int o = 1; o < 256; o <<= 1) {
    int x = (t >= o) ? sm[t - o] : 0;
    __syncthreads();
    sm[t] += x;
    __syncthreads();
  }
  if (i < NNODES) off[i] = sm[t] - v;
  if (t == 255) part[b] = sm[t];
}

__global__ __launch_bounds__(256) void scan2(int* __restrict__ part) {
  int t = threadIdx.x;
  int v = (t < SCAN_NB) ? part[t] : 0;
  __shared__ int sm[256];
  sm[t] = v;
  __syncthreads();
#pragma unroll
  for (int o = 1; o < 256; o <<= 1) {
    int x = (t >= o) ? sm[t - o] : 0;
    __syncthreads();
    sm[t] += x;
    __syncthreads();
  }
  if (t < SCAN_NB) part[t] = sm[t] - v;
}

__global__ __launch_bounds__(256) void scan3(int* __restrict__ off, const int* __restrict__ part) {
  int i = blockIdx.x * 256 + threadIdx.x;
  if (i < NNODES) off[i] += part[blockIdx.x];
  if (i == 0) off[NNODES] = NEDGE;
}

__global__ __launch_bounds__(256) void scatter_edges(
    const int* __restrict__ src, const int* __restrict__ dst, const int* __restrict__ et,
    const int* __restrict__ cnt, const int* __restrict__ off,
    int* __restrict__ fill, unsigned* __restrict__ sorted, float* __restrict__ scales) {
  int e = blockIdx.x * 256 + threadIdx.x;
  if (e >= NEDGE) return;
  int d = dst[e], r = et[e], s = src[e];
  int pos = off[d] + atomicAdd(&fill[d], 1);
  sorted[pos] = (unsigned)s | ((unsigned)r << 16);
  scales[pos] = 1.0f / (float)cnt[r * NNODES + d];
}

// ---------------- fused layer1: 4-way unrolled segmented mean-agg + relu ----------
__global__ __launch_bounds__(256) void fused1(
    const int* __restrict__ off, const unsigned* __restrict__ sorted,
    const float* __restrict__ scales, const ushort* __restrict__ Y1,
    const float* __restrict__ b1, __hip_bfloat16* __restrict__ x1b) {
  int w = threadIdx.x >> 6, lane = threadIdx.x & 63;
  int d = blockIdx.x * 4 + w;
  int s0 = off[d], s1 = off[d + 1];
  float a0 = bfu(Y1[(size_t)d * 1088 + lane]) + b1[lane];
  float a1 = 0.f, a2 = 0.f, a3 = 0.f;
  int i = s0;
  for (; i + 3 < s1; i += 4) {
    unsigned p0 = sorted[i], p1 = sorted[i + 1], p2 = sorted[i + 2], p3 = sorted[i + 3];
    float c0 = scales[i], c1 = scales[i + 1], c2 = scales[i + 2], c3 = scales[i + 3];
    a0 += bfu(Y1[(size_t)(p0 & 0xFFFF) * 1088 + 64 + (p0 >> 16) * 64 + lane]) * c0;
    a1 += bfu(Y1[(size_t)(p1 & 0xFFFF) * 1088 + 64 + (p1 >> 16) * 64 + lane]) * c1;
    a2 += bfu(Y1[(size_t)(p2 & 0xFFFF) * 1088 + 64 + (p2 >> 16) * 64 + lane]) * c2;
    a3 += bfu(Y1[(size_t)(p3 & 0xFFFF) * 1088 + 64 + (p3 >> 16) * 64 + lane]) * c3;
  }
  for (; i < s1; i++) {
    unsigned p = sorted[i];
    a0 += bfu(Y1[(size_t)(p & 0xFFFF) * 1088 + 64 + (p >> 16) * 64 + lane]) * scales[i];
  }
  float acc = (a0 + a1) + (a2 + a3);
  x1b[(size_t)d * 64 + lane] = __float2bfloat16(fmaxf(acc, 0.f));
}

// ---------------- fused layer2: 4-way (2 lanes x 2 accs) + softmax -> out ---------
__global__ __launch_bounds__(256) void fused2(
    const int* __restrict__ off, const unsigned* __restrict__ sorted,
    const float* __restrict__ scales, const ushort* __restrict__ Y2,
    const float* __restrict__ b2, float* __restrict__ out) {
  int w = threadIdx.x >> 6, lane = threadIdx.x & 63;
  int d = blockIdx.x * 4 + w;
  int j = lane & 31, half = lane >> 5;
  int s0 = off[d], s1 = off[d + 1];
  float a0 = 0.f, a1 = 0.f;
  int i = s0 + half;
  for (; i + 2 < s1; i += 4) {
    unsigned p0 = sorted[i], p1 = sorted[i + 2];
    a0 += bfu(Y2[(size_t)(p0 & 0xFFFF) * 544 + 32 + (p0 >> 16) * 32 + j]) * scales[i];
    a1 += bfu(Y2[(size_t)(p1 & 0xFFFF) * 544 + 32 + (p1 >> 16) * 32 + j]) * scales[i + 2];
  }
  for (; i < s1; i += 2) {
    unsigned p = sorted[i];
    a0 += bfu(Y2[(size_t)(p & 0xFFFF) * 544 + 32 + (p >> 16) * 32 + j]) * scales[i];
  }
  float acc = a0 + a1;
  acc += __shfl_xor(acc, 32);
  float v = acc + bfu(Y2[(size_t)d * 544 + j]) + b2[j];
  float mx = v;
#pragma unroll
  for (int o = 16; o; o >>= 1) mx = fmaxf(mx, __shfl_xor(mx, o));
  float e = __expf(v - mx);
  float sum = e;
#pragma unroll
  for (int o = 16; o; o >>= 1) sum += __shfl_xor(sum, o);
  if (half == 0) out[(size_t)d * 32 + j] = e / sum;
}

// =================================================================================
extern "C" void kernel_launch(void* const* d_in, const int* in_sizes, int n_in,
                              void* d_out, int out_size, void* d_ws, size_t ws_size,
                              hipStream_t stream) {
  (void)in_sizes; (void)n_in; (void)out_size; (void)ws_size;
  const float* emb   = (const float*)d_in[0];
  const float* ipw   = (const float*)d_in[1];
  const float* ipb   = (const float*)d_in[2];
  const float* opw   = (const float*)d_in[3];
  const float* opb   = (const float*)d_in[4];
  const float* w1    = (const float*)d_in[5];
  const float* root1 = (const float*)d_in[6];
  const float* b1    = (const float*)d_in[7];
  const float* w2    = (const float*)d_in[8];
  const float* root2 = (const float*)d_in[9];
  const float* b2    = (const float*)d_in[10];
  const int*   eidx  = (const int*)d_in[11];
  const int*   etype = (const int*)d_in[12];
  const int* srcp = eidx;
  const int* dstp = eidx + NEDGE;

  unsigned char* ws = (unsigned char*)d_ws;
  size_t off_b = 0;
  auto alloc = [&](size_t bytes) {
    unsigned char* p = ws + off_b;
    off_b += (bytes + 255) & ~(size_t)255;
    return p;
  };

  // Region R reused sequentially: qkv 153.6MB -> Y1 108.8MB -> Y2 54.4MB
  unsigned char* R = alloc(153600000);
  __hip_bfloat16* qkv = (__hip_bfloat16*)R;
  __hip_bfloat16* Y1  = (__hip_bfloat16*)R;
  __hip_bfloat16* Y2  = (__hip_bfloat16*)R;
  __hip_bfloat16* o0  = (__hip_bfloat16*)alloc(12800000);
  __hip_bfloat16* x1b = (__hip_bfloat16*)alloc(6400000);
  int*            cnt = (int*)alloc(3200000);
  int*            offs = (int*)alloc((NNODES + 1) * 4);
  int*            fill = (int*)alloc(NNODES * 4);
  int*            part = (int*)alloc(SCAN_NB * 4);
  unsigned*       sorted = (unsigned*)alloc(NEDGE * 4);
  float*          scales = (float*)alloc(NEDGE * 4);
  __hip_bfloat16* BTqkv  = (__hip_bfloat16*)alloc(98304);
  __hip_bfloat16* BToutT = (__hip_bfloat16*)alloc(32768);
  __hip_bfloat16* BT1    = (__hip_bfloat16*)alloc(278528);
  __hip_bfloat16* BT2    = (__hip_bfloat16*)alloc(69632);
  __hip_bfloat16* BW     = (__hip_bfloat16*)alloc(278528);  // 1088 x 128
  float*          bias1  = (float*)alloc(4352);

  // 1) weight prep + CSR build
  prep_weights<<<dim3((241664 + 255) / 256), dim3(256), 0, stream>>>(
      ipw, opw, w1, root1, w2, root2, BTqkv, BToutT, BT1, BT2);
  prep_bias1<<<dim3(5), dim3(256), 0, stream>>>(opb, w1, root1, bias1);
  hipMemsetAsync(cnt, 0, (size_t)RREL * NNODES * sizeof(int), stream);
  hipMemsetAsync(fill, 0, (size_t)NNODES * sizeof(int), stream);
  count_edges<<<dim3((NEDGE + 255) / 256), dim3(256), 0, stream>>>(dstp, etype, cnt);
  scan1<<<dim3(SCAN_NB), dim3(256), 0, stream>>>(cnt, offs, part);
  scan2<<<dim3(1), dim3(256), 0, stream>>>(part);
  scan3<<<dim3(SCAN_NB), dim3(256), 0, stream>>>(offs, part);
  scatter_edges<<<dim3((NEDGE + 255) / 256), dim3(256), 0, stream>>>(
      srcp, dstp, etype, cnt, offs, fill, sorted, scales);

  // 2) BW = (Wo^T B1) fold: (1088 x 128) = BT1 @ BToutT^T
  gemm_strips<128><<<dim3(9, 1), dim3(256), 0, stream>>>(
      BT1, BToutT, nullptr, BW, 1088, 128, 128, 1);

  // 3) QKV (strip-loop): (200000 x 128 f32) @ (128 x 384) -> qkv
  qkv_gemm<<<dim3(1563), dim3(256), 0, stream>>>(emb, BTqkv, ipb, qkv);

  // 4) attention -> o0
  attn_kernel<<<dim3(12500), dim3(256), 0, stream>>>(qkv, o0);

  // 5) Y1 = o0 @ BW (+bias1): (50000 x 128) @ (128 x 1088), 9 strips in 3 groups
  gemm_strips<128><<<dim3(391, 3), dim3(256), 0, stream>>>(
      o0, BW, bias1, Y1, NNODES, 1088, 1088, 3);

  // 6) fused layer1 -> x1b
  fused1<<<dim3(NNODES / 4), dim3(256), 0, stream>>>(
      offs, sorted, scales, (const ushort*)Y1, b1, x1b);

  // 7) Y2 = x1b @ [root2 | W2_r]: (50000 x 64) @ (64 x 544), 5 strips in 2 groups
  gemm_strips<64><<<dim3(391, 2), dim3(256), 0, stream>>>(
      x1b, BT2, nullptr, Y2, NNODES, 544, 544, 3);

  // 8) fused layer2 + softmax -> out
  fused2<<<dim3(NNODES / 4), dim3(256), 0, stream>>>(
      offs, sorted, scales, (const ushort*)Y2, b2, (float*)d_out);
}

// Round 13
// 339.016 us; speedup vs baseline: 1.3477x; 1.0036x over previous
//
#include <hip/hip_runtime.h>
#include <hip/hip_bf16.h>
#include <math.h>

#define NNODES 50000
#define NEDGE 625000
#define RREL 16
#define SCAN_NB 196   // ceil(50000/256)

typedef __attribute__((ext_vector_type(8))) short short8;
typedef __attribute__((ext_vector_type(4))) float f32x4;

__device__ __forceinline__ float bfu(ushort u) {
  return __uint_as_float(((unsigned)u) << 16);
}
__device__ __forceinline__ ushort f2b(float f) {
  __hip_bfloat16 h = __float2bfloat16(f);
  return *(ushort*)&h;
}

// ---------------- weight prep: bf16, B stored transposed (N x K, K contiguous) ----
__global__ __launch_bounds__(256) void prep_weights(
    const float* __restrict__ ipw, const float* __restrict__ opw,
    const float* __restrict__ w1, const float* __restrict__ root1,
    const float* __restrict__ w2, const float* __restrict__ root2,
    __hip_bfloat16* __restrict__ BTqkv, __hip_bfloat16* __restrict__ BToutT,
    __hip_bfloat16* __restrict__ BT1, __hip_bfloat16* __restrict__ BT2) {
  int i = blockIdx.x * 256 + threadIdx.x;
  if (i < 49152) {
    BTqkv[i] = __float2bfloat16(ipw[i]);
  } else if (i < 65536) {
    int j = i - 49152; int m = j / 128, c = j % 128;
    BToutT[j] = __float2bfloat16(opw[c * 128 + m]);
  } else if (i < 65536 + 139264) {
    int j = i - 65536; int c = j / 128, k = j % 128;
    float v;
    if (c < 64) v = root1[k * 64 + c];
    else { int r = (c - 64) >> 6, o = (c - 64) & 63; v = w1[r * 8192 + k * 64 + o]; }
    BT1[j] = __float2bfloat16(v);
  } else if (i < 65536 + 139264 + 34816) {
    int j = i - 65536 - 139264; int c = j / 64, k = j % 64;
    float v;
    if (c < 32) v = root2[k * 32 + c];
    else { int r = (c - 32) >> 5, o = (c - 32) & 31; v = w2[r * 2048 + k * 32 + o]; }
    BT2[j] = __float2bfloat16(v);
  }
}

// ---------------- bias1' = bo @ B1 (f32), 1088 outputs ----------------------------
__global__ __launch_bounds__(256) void prep_bias1(
    const float* __restrict__ opb, const float* __restrict__ w1,
    const float* __restrict__ root1, float* __restrict__ bias1) {
  int j = blockIdx.x * 256 + threadIdx.x;
  if (j >= 1088) return;
  float s = 0.f;
  if (j < 64) {
    for (int c = 0; c < 128; c++) s += opb[c] * root1[c * 64 + j];
  } else {
    int r = (j - 64) >> 6, o = (j - 64) & 63;
    for (int c = 0; c < 128; c++) s += opb[c] * w1[r * 8192 + c * 64 + o];
  }
  bias1[j] = s;
}

// ---------------- attn_mega: QKV proj + attention fused at block scope ------------
// Block = 32 nodes x 4 levels. Wave w owns level l=w's 32 rows: A-frags in regs
// (f32->bf16), K/V 32x128 sub-tiles -> LDS (bias folded). Wave 0 also computes
// Q (l=0, alpha+bias folded) -> Qs. One barrier, then each wave does the
// per-node attention for 8 nodes from LDS. Output: o0 (l=0 only).
__global__ __launch_bounds__(256) void attn_mega(
    const float* __restrict__ emb, const __hip_bfloat16* __restrict__ BTqkv,
    const float* __restrict__ ipb, __hip_bfloat16* __restrict__ o0) {
  __shared__ ushort Ks[128 * 132];  // 33.8KB
  __shared__ ushort Vs[128 * 132];  // 33.8KB
  __shared__ ushort Qs[32 * 132];   //  8.4KB  (total ~76KB -> 2 blocks/CU)
  const ushort* BT = (const ushort*)BTqkv;
  const int t = threadIdx.x;
  const int w = t >> 6, lane = t & 63;
  const int lrow = lane & 15, lk = lane >> 4;
  const long nb = (long)blockIdx.x * 32;

  // ---- A fragments: wave w = level w, nodes nb+16i+lrow ----
  short8 af[2][4];
#pragma unroll
  for (int i = 0; i < 2; i++) {
    long n = nb + 16 * i + lrow;
    if (n > NNODES - 1) n = NNODES - 1;
    const float* ap = emb + ((long)w * NNODES + n) * 128;
#pragma unroll
    for (int k0 = 0; k0 < 4; k0++) {
      float4 f0 = *(const float4*)(ap + k0 * 32 + lk * 8);
      float4 f1 = *(const float4*)(ap + k0 * 32 + lk * 8 + 4);
      int4 v;
      v.x = (int)f2b(f0.x) | ((int)f2b(f0.y) << 16);
      v.y = (int)f2b(f0.z) | ((int)f2b(f0.w) << 16);
      v.z = (int)f2b(f1.x) | ((int)f2b(f1.y) << 16);
      v.w = (int)f2b(f1.z) | ((int)f2b(f1.w) << 16);
      af[i][k0] = *(short8*)&v;
    }
  }

  const float alpha = 0.17677669529663687f;  // 1/sqrt(32)

  // ---- Q strip (wave 0 only): cols 0..127 of BTqkv, rows l=0 ----
  if (w == 0) {
#pragma unroll
    for (int half = 0; half < 2; half++) {
      f32x4 acc[2][4];
#pragma unroll
      for (int i = 0; i < 2; i++)
#pragma unroll
        for (int j = 0; j < 4; j++) acc[i][j] = (f32x4){0.f, 0.f, 0.f, 0.f};
#pragma unroll
      for (int k0 = 0; k0 < 4; k0++) {
        short8 bfr[4];
#pragma unroll
        for (int j = 0; j < 4; j++)
          bfr[j] = *(const short8*)(BT + (long)(half * 64 + j * 16 + lrow) * 128 + k0 * 32 + lk * 8);
#pragma unroll
        for (int i = 0; i < 2; i++)
#pragma unroll
          for (int j = 0; j < 4; j++)
            acc[i][j] = __builtin_amdgcn_mfma_f32_16x16x32_bf16(af[i][k0], bfr[j], acc[i][j], 0, 0, 0);
      }
#pragma unroll
      for (int j = 0; j < 4; j++) {
        int c = half * 64 + j * 16 + lrow;
        float bq = ipb[c];
#pragma unroll
        for (int i = 0; i < 2; i++)
#pragma unroll
          for (int q = 0; q < 4; q++)
            Qs[(16 * i + 4 * lk + q) * 132 + c] = f2b((acc[i][j][q] + bq) * alpha);
      }
    }
  }

  // ---- K and V strips: all waves, rows l=w -> Ks/Vs rows 32w.. ----
#pragma unroll
  for (int sidx = 0; sidx < 2; sidx++) {       // 0 = K, 1 = V
    const int base = 128 + sidx * 128;
    ushort* dst = sidx ? Vs : Ks;
#pragma unroll
    for (int half = 0; half < 2; half++) {
      f32x4 acc[2][4];
#pragma unroll
      for (int i = 0; i < 2; i++)
#pragma unroll
        for (int j = 0; j < 4; j++) acc[i][j] = (f32x4){0.f, 0.f, 0.f, 0.f};
#pragma unroll
      for (int k0 = 0; k0 < 4; k0++) {
        short8 bfr[4];
#pragma unroll
        for (int j = 0; j < 4; j++)
          bfr[j] = *(const short8*)(BT + (long)(base + half * 64 + j * 16 + lrow) * 128 + k0 * 32 + lk * 8);
#pragma unroll
        for (int i = 0; i < 2; i++)
#pragma unroll
          for (int j = 0; j < 4; j++)
            acc[i][j] = __builtin_amdgcn_mfma_f32_16x16x32_bf16(af[i][k0], bfr[j], acc[i][j], 0, 0, 0);
      }
#pragma unroll
      for (int j = 0; j < 4; j++) {
        int c = half * 64 + j * 16 + lrow;
        float bv = ipb[base + c];
#pragma unroll
        for (int i = 0; i < 2; i++)
#pragma unroll
          for (int q = 0; q < 4; q++)
            dst[(32 * w + 16 * i + 4 * lk + q) * 132 + c] = f2b(acc[i][j][q] + bv);
      }
    }
  }
  __syncthreads();

  // ---- attention: wave w handles nodes 8w .. 8w+7 ----
  for (int ii = 0; ii < 8; ii++) {
    int i = 8 * w + ii;
    long n = nb + i;
    uint qv = *(const uint*)(Qs + i * 132 + lane * 2);
    float q0 = bfu(qv & 0xffff), q1 = bfu(qv >> 16);
    float s[4];
#pragma unroll
    for (int m = 0; m < 4; m++) {
      uint kk = *(const uint*)(Ks + (m * 32 + i) * 132 + lane * 2);
      float p = q0 * bfu(kk & 0xffff) + q1 * bfu(kk >> 16);
#pragma unroll
      for (int off = 8; off; off >>= 1) p += __shfl_xor(p, off);
      s[m] = p;  // alpha already folded into Q
    }
    float mx = fmaxf(fmaxf(s[0], s[1]), fmaxf(s[2], s[3]));
    float e[4], sum = 0.f;
#pragma unroll
    for (int m = 0; m < 4; m++) { e[m] = __expf(s[m] - mx); sum += e[m]; }
    float inv = 1.0f / sum;
    float o0f = 0.f, o1f = 0.f;
#pragma unroll
    for (int m = 0; m < 4; m++) {
      uint vv = *(const uint*)(Vs + (m * 32 + i) * 132 + lane * 2);
      float wgt = e[m] * inv;
      o0f += wgt * bfu(vv & 0xffff);
      o1f += wgt * bfu(vv >> 16);
    }
    if (n < NNODES)
      *(uint*)((ushort*)o0 + n * 128 + lane * 2) = (uint)f2b(o0f) | ((uint)f2b(o1f) << 16);
  }
}

// ---------------- generic strip-loop bf16 GEMM (B direct from L2) -----------------
#define EPILOGUE_STORE(MEFF, NCOLS, LDC, BIASEXPR)                              \
  for (int p = 0; p < 2; p++) {                                                 \
    __syncthreads();                                                            \
    if ((w >> 1) == p) {                                                        \
      _Pragma("unroll")                                                         \
      for (int j = 0; j < 4; j++) {                                             \
        int coll = wc + j * 16 + lrow;                                          \
        float bv = (BIASEXPR);                                                  \
        _Pragma("unroll")                                                       \
        for (int i = 0; i < 4; i++) {                                           \
          int rloc = i * 16 + lk * 4;                                           \
          _Pragma("unroll")                                                     \
          for (int q = 0; q < 4; q++)                                           \
            Cs[(rloc + q) * 132 + coll] = f2b(acc[i][j][q] + bv);               \
        }                                                                       \
      }                                                                         \
    }                                                                           \
    __syncthreads();                                                            \
    _Pragma("unroll")                                                           \
    for (int idx = t; idx < 64 * 16; idx += 256) {                              \
      int r = idx >> 4, k = idx & 15;                                           \
      long gm = row0 + p * 64 + r;                                              \
      int col = col0 + k * 8;                                                   \
      if (gm < (MEFF) && col < (NCOLS))                                         \
        *(int4*)((ushort*)C + gm * (LDC) + col) = *(const int4*)(Cs + r * 132 + k * 8); \
    }                                                                           \
  }

template <int K>
__global__ __launch_bounds__(256) void gemm_strips(
    const __hip_bfloat16* __restrict__ Av, const __hip_bfloat16* __restrict__ BT,
    const float* __restrict__ bias, __hip_bfloat16* __restrict__ C,
    int M, int N, int ldc, int spg) {
  constexpr int CPR = K / 8;
  __shared__ ushort As[128 * K];
  __shared__ ushort Cs[64 * 132];
  const int t = threadIdx.x;
  const long row0 = (long)blockIdx.x * 128;

#pragma unroll
  for (int c = t; c < 128 * CPR; c += 256) {
    int r = c / CPR, cc = c % CPR;
    long gm = row0 + r;
    int4 v = make_int4(0, 0, 0, 0);
    if (gm < M) v = *(const int4*)((const ushort*)Av + gm * K + cc * 8);
    *(int4*)(As + r * K + ((cc ^ (r & 7)) * 8)) = v;
  }
  __syncthreads();

  const int lane = t & 63, w = t >> 6;
  const int wr = (w >> 1) * 64, wc = (w & 1) * 64;
  const int lrow = lane & 15, lk = lane >> 4;
  const int nstrips = (N + 127) / 128;
  const int sbeg = blockIdx.y * spg;
  const int send = min(sbeg + spg, nstrips);

  for (int s = sbeg; s < send; s++) {
    const int col0 = s * 128;

    const ushort* bp[4];
#pragma unroll
    for (int j = 0; j < 4; j++) {
      int gn = col0 + wc + j * 16 + lrow;
      if (gn > N - 1) gn = N - 1;
      bp[j] = (const ushort*)BT + (long)gn * K + lk * 8;
    }

    f32x4 acc[4][4];
#pragma unroll
    for (int i = 0; i < 4; i++)
#pragma unroll
      for (int j = 0; j < 4; j++) acc[i][j] = (f32x4){0.f, 0.f, 0.f, 0.f};

#pragma unroll
    for (int k0 = 0; k0 < K; k0 += 32) {
      const int cb = k0 / 8 + lk;
      short8 af[4], bfr[4];
#pragma unroll
      for (int j = 0; j < 4; j++) bfr[j] = *(const short8*)(bp[j] + k0);
#pragma unroll
      for (int i = 0; i < 4; i++) {
        int ra = wr + i * 16 + lrow;
        af[i] = *(const short8*)(As + ra * K + ((cb ^ (ra & 7)) * 8));
      }
#pragma unroll
      for (int i = 0; i < 4; i++)
#pragma unroll
        for (int j = 0; j < 4; j++)
          acc[i][j] = __builtin_amdgcn_mfma_f32_16x16x32_bf16(af[i], bfr[j], acc[i][j], 0, 0, 0);
    }

    EPILOGUE_STORE(M, N, ldc, bias ? bias[min(col0 + coll, N - 1)] : 0.f)
  }
}

// ---------------- edge counts per (r, dst) ---------------------------------------
__global__ __launch_bounds__(256) void count_edges(
    const int* __restrict__ dst, const int* __restrict__ et, int* __restrict__ cnt) {
  int e = blockIdx.x * 256 + threadIdx.x;
  if (e < NEDGE) atomicAdd(&cnt[et[e] * NNODES + dst[e]], 1);
}

// ---------------- CSR build ------------------------------------------------------
__global__ __launch_bounds__(256) void scan1(
    const int* __restrict__ cnt, int* __restrict__ off, int* __restrict__ part) {
  int t = threadIdx.x, b = blockIdx.x;
  int i = b * 256 + t;
  int v = 0;
  if (i < NNODES) {
#pragma unroll
    for (int r = 0; r < RREL; r++) v += cnt[r * NNODES + i];
  }
  __shared__ int sm[256];
  sm[t] = v;
  __syncthreads();
#pragma unroll
  for (int o = 1; o < 256; o <<= 1) {
    int x = (t >= o) ? sm[t - o] : 0;
    __syncthreads();
    sm[t] += x;
    __syncthreads();
  }
  if (i < NNODES) off[i] = sm[t] - v;
  if (t == 255) part[b] = sm[t];
}

__global__ __launch_bounds__(256) void scan2(int* __restrict__ part) {
  int t = threadIdx.x;
  int v = (t < SCAN_NB) ? part[t] : 0;
  __shared__ int sm[256];
  sm[t] = v;
  __syncthreads();
#pragma unroll
  for (int o = 1; o < 256; o <<= 1) {
    int x = (t >= o) ? sm[t - o] : 0;
    __syncthreads();
    sm[t] += x;
    __syncthreads();
  }
  if (t < SCAN_NB) part[t] = sm[t] - v;
}

__global__ __launch_bounds__(256) void scan3(int* __restrict__ off, const int* __restrict__ part) {
  int i = blockIdx.x * 256 + threadIdx.x;
  if (i < NNODES) off[i] += part[blockIdx.x];
  if (i == 0) off[NNODES] = NEDGE;
}

__global__ __launch_bounds__(256) void scatter_edges(
    const int* __restrict__ src, const int* __restrict__ dst, const int* __restrict__ et,
    const int* __restrict__ cnt, const int* __restrict__ off,
    int* __restrict__ fill, unsigned* __restrict__ sorted, float* __restrict__ scales) {
  int e = blockIdx.x * 256 + threadIdx.x;
  if (e >= NEDGE) return;
  int d = dst[e], r = et[e], s = src[e];
  int pos = off[d] + atomicAdd(&fill[d], 1);
  sorted[pos] = (unsigned)s | ((unsigned)r << 16);
  scales[pos] = 1.0f / (float)cnt[r * NNODES + d];
}

// ---------------- fused layer1: 4-way unrolled segmented mean-agg + relu ----------
__global__ __launch_bounds__(256) void fused1(
    const int* __restrict__ off, const unsigned* __restrict__ sorted,
    const float* __restrict__ scales, const ushort* __restrict__ Y1,
    const float* __restrict__ b1, __hip_bfloat16* __restrict__ x1b) {
  int w = threadIdx.x >> 6, lane = threadIdx.x & 63;
  int d = blockIdx.x * 4 + w;
  int s0 = off[d], s1 = off[d + 1];
  float a0 = bfu(Y1[(size_t)d * 1088 + lane]) + b1[lane];
  float a1 = 0.f, a2 = 0.f, a3 = 0.f;
  int i = s0;
  for (; i + 3 < s1; i += 4) {
    unsigned p0 = sorted[i], p1 = sorted[i + 1], p2 = sorted[i + 2], p3 = sorted[i + 3];
    float c0 = scales[i], c1 = scales[i + 1], c2 = scales[i + 2], c3 = scales[i + 3];
    a0 += bfu(Y1[(size_t)(p0 & 0xFFFF) * 1088 + 64 + (p0 >> 16) * 64 + lane]) * c0;
    a1 += bfu(Y1[(size_t)(p1 & 0xFFFF) * 1088 + 64 + (p1 >> 16) * 64 + lane]) * c1;
    a2 += bfu(Y1[(size_t)(p2 & 0xFFFF) * 1088 + 64 + (p2 >> 16) * 64 + lane]) * c2;
    a3 += bfu(Y1[(size_t)(p3 & 0xFFFF) * 1088 + 64 + (p3 >> 16) * 64 + lane]) * c3;
  }
  for (; i < s1; i++) {
    unsigned p = sorted[i];
    a0 += bfu(Y1[(size_t)(p & 0xFFFF) * 1088 + 64 + (p >> 16) * 64 + lane]) * scales[i];
  }
  float acc = (a0 + a1) + (a2 + a3);
  x1b[(size_t)d * 64 + lane] = __float2bfloat16(fmaxf(acc, 0.f));
}

// ---------------- fused layer2: 4-way (2 lanes x 2 accs) + softmax -> out ---------
__global__ __launch_bounds__(256) void fused2(
    const int* __restrict__ off, const unsigned* __restrict__ sorted,
    const float* __restrict__ scales, const ushort* __restrict__ Y2,
    const float* __restrict__ b2, float* __restrict__ out) {
  int w = threadIdx.x >> 6, lane = threadIdx.x & 63;
  int d = blockIdx.x * 4 + w;
  int j = lane & 31, half = lane >> 5;
  int s0 = off[d], s1 = off[d + 1];
  float a0 = 0.f, a1 = 0.f;
  int i = s0 + half;
  for (; i + 2 < s1; i += 4) {
    unsigned p0 = sorted[i], p1 = sorted[i + 2];
    a0 += bfu(Y2[(size_t)(p0 & 0xFFFF) * 544 + 32 + (p0 >> 16) * 32 + j]) * scales[i];
    a1 += bfu(Y2[(size_t)(p1 & 0xFFFF) * 544 + 32 + (p1 >> 16) * 32 + j]) * scales[i + 2];
  }
  for (; i < s1; i += 2) {
    unsigned p = sorted[i];
    a0 += bfu(Y2[(size_t)(p & 0xFFFF) * 544 + 32 + (p >> 16) * 32 + j]) * scales[i];
  }
  float acc = a0 + a1;
  acc += __shfl_xor(acc, 32);
  float v = acc + bfu(Y2[(size_t)d * 544 + j]) + b2[j];
  float mx = v;
#pragma unroll
  for (int o = 16; o; o >>= 1) mx = fmaxf(mx, __shfl_xor(mx, o));
  float e = __expf(v - mx);
  float sum = e;
#pragma unroll
  for (int o = 16; o; o >>= 1) sum += __shfl_xor(sum, o);
  if (half == 0) out[(size_t)d * 32 + j] = e / sum;
}

// =================================================================================
extern "C" void kernel_launch(void* const* d_in, const int* in_sizes, int n_in,
                              void* d_out, int out_size, void* d_ws, size_t ws_size,
                              hipStream_t stream) {
  (void)in_sizes; (void)n_in; (void)out_size; (void)ws_size;
  const float* emb   = (const float*)d_in[0];
  const float* ipw   = (const float*)d_in[1];
  const float* ipb   = (const float*)d_in[2];
  const float* opw   = (const float*)d_in[3];
  const float* opb   = (const float*)d_in[4];
  const float* w1    = (const float*)d_in[5];
  const float* root1 = (const float*)d_in[6];
  const float* b1    = (const float*)d_in[7];
  const float* w2    = (const float*)d_in[8];
  const float* root2 = (const float*)d_in[9];
  const float* b2    = (const float*)d_in[10];
  const int*   eidx  = (const int*)d_in[11];
  const int*   etype = (const int*)d_in[12];
  const int* srcp = eidx;
  const int* dstp = eidx + NEDGE;

  unsigned char* ws = (unsigned char*)d_ws;
  size_t off_b = 0;
  auto alloc = [&](size_t bytes) {
    unsigned char* p = ws + off_b;
    off_b += (bytes + 255) & ~(size_t)255;
    return p;
  };

  // Region R reused sequentially: Y1 108.8MB -> Y2 54.4MB
  unsigned char* R = alloc(108800000);
  __hip_bfloat16* Y1  = (__hip_bfloat16*)R;
  __hip_bfloat16* Y2  = (__hip_bfloat16*)R;
  __hip_bfloat16* o0  = (__hip_bfloat16*)alloc(12800000);
  __hip_bfloat16* x1b = (__hip_bfloat16*)alloc(6400000);
  int*            cnt = (int*)alloc(3200000);
  int*            offs = (int*)alloc((NNODES + 1) * 4);
  int*            fill = (int*)alloc(NNODES * 4);
  int*            part = (int*)alloc(SCAN_NB * 4);
  unsigned*       sorted = (unsigned*)alloc(NEDGE * 4);
  float*          scales = (float*)alloc(NEDGE * 4);
  __hip_bfloat16* BTqkv  = (__hip_bfloat16*)alloc(98304);
  __hip_bfloat16* BToutT = (__hip_bfloat16*)alloc(32768);
  __hip_bfloat16* BT1    = (__hip_bfloat16*)alloc(278528);
  __hip_bfloat16* BT2    = (__hip_bfloat16*)alloc(69632);
  __hip_bfloat16* BW     = (__hip_bfloat16*)alloc(278528);  // 1088 x 128
  float*          bias1  = (float*)alloc(4352);

  // 1) weight prep + CSR build
  prep_weights<<<dim3((241664 + 255) / 256), dim3(256), 0, stream>>>(
      ipw, opw, w1, root1, w2, root2, BTqkv, BToutT, BT1, BT2);
  prep_bias1<<<dim3(5), dim3(256), 0, stream>>>(opb, w1, root1, bias1);
  hipMemsetAsync(cnt, 0, (size_t)RREL * NNODES * sizeof(int), stream);
  hipMemsetAsync(fill, 0, (size_t)NNODES * sizeof(int), stream);
  count_edges<<<dim3((NEDGE + 255) / 256), dim3(256), 0, stream>>>(dstp, etype, cnt);
  scan1<<<dim3(SCAN_NB), dim3(256), 0, stream>>>(cnt, offs, part);
  scan2<<<dim3(1), dim3(256), 0, stream>>>(part);
  scan3<<<dim3(SCAN_NB), dim3(256), 0, stream>>>(offs, part);
  scatter_edges<<<dim3((NEDGE + 255) / 256), dim3(256), 0, stream>>>(
      srcp, dstp, etype, cnt, offs, fill, sorted, scales);

  // 2) BW = (Wo^T B1) fold: (1088 x 128) = BT1 @ BToutT^T
  gemm_strips<128><<<dim3(9, 1), dim3(256), 0, stream>>>(
      BT1, BToutT, nullptr, BW, 1088, 128, 128, 1);

  // 3) fused QKV + attention -> o0 (block = 32 nodes x 4 levels)
  attn_mega<<<dim3((NNODES + 31) / 32), dim3(256), 0, stream>>>(
      emb, BTqkv, ipb, o0);

  // 4) Y1 = o0 @ BW (+bias1): (50000 x 128) @ (128 x 1088), 9 strips in 3 groups
  gemm_strips<128><<<dim3(391, 3), dim3(256), 0, stream>>>(
      o0, BW, bias1, Y1, NNODES, 1088, 1088, 3);

  // 5) fused layer1 -> x1b
  fused1<<<dim3(NNODES / 4), dim3(256), 0, stream>>>(
      offs, sorted, scales, (const ushort*)Y1, b1, x1b);

  // 6) Y2 = x1b @ [root2 | W2_r]: (50000 x 64) @ (64 x 544), 5 strips in 2 groups
  gemm_strips<64><<<dim3(391, 2), dim3(256), 0, stream>>>(
      x1b, BT2, nullptr, Y2, NNODES, 544, 544, 3);

  // 7) fused layer2 + softmax -> out
  fused2<<<dim3(NNODES / 4), dim3(256), 0, stream>>>(
      offs, sorted, scales, (const ushort*)Y2, b2, (float*)d_out);
}